// Round 21
// baseline (207.339 us; speedup 1.0000x reference)
//
#include <hip/hip_runtime.h>
#include <hip/hip_bf16.h>

#define T_TOK   13294
#define BS_     2
#define M_ROWS  (BS_ * T_TOK)   // 26588
#define EMBED_  256
#define HID_    1024

typedef __attribute__((ext_vector_type(8))) short short8;
typedef __attribute__((ext_vector_type(4))) float f32x4;

__device__ __forceinline__ unsigned short f2bf(float f) {
  __hip_bfloat16 h = __float2bfloat16(f);
  return *reinterpret_cast<unsigned short*>(&h);
}
__device__ __forceinline__ float bf2f(unsigned short u) {
  unsigned int x = ((unsigned int)u) << 16;
  return __uint_as_float(x);
}

// ---------------------------------------------------------------------------
// Fused prep: blocks 0..735 = weight transpose+bf16; rest = LN1 (+pos).
// ---------------------------------------------------------------------------
__global__ __launch_bounds__(256) void prep_kernel(
    const float* __restrict__ s0, const float* __restrict__ s1,
    const float* __restrict__ s2, const float* __restrict__ s3,
    const float* __restrict__ s4, const float* __restrict__ s5,
    unsigned short* __restrict__ d0, unsigned short* __restrict__ d1,
    unsigned short* __restrict__ d2, unsigned short* __restrict__ d3,
    unsigned short* __restrict__ d4, unsigned short* __restrict__ d5,
    const float* __restrict__ x, const float* __restrict__ pos,
    const float* __restrict__ g, const float* __restrict__ bta,
    unsigned short* __restrict__ y, unsigned short* __restrict__ q) {
  const int bid = blockIdx.x;
  if (bid < 736) {
    __shared__ float t[32][33];
    const float* S; unsigned short* D; int K, N, t0;
    if      (bid <  64) { S = s0; D = d0; K = 256;  N = 256;  t0 = 0;   }
    else if (bid < 128) { S = s1; D = d1; K = 256;  N = 256;  t0 = 64;  }
    else if (bid < 160) { S = s2; D = d2; K = 256;  N = 128;  t0 = 128; }
    else if (bid < 224) { S = s3; D = d3; K = 256;  N = 256;  t0 = 160; }
    else if (bid < 480) { S = s4; D = d4; K = 256;  N = 1024; t0 = 224; }
    else                { S = s5; D = d5; K = 1024; N = 256;  t0 = 480; }
    const int tile = bid - t0;
    const int ntx = N >> 5;
    const int k0 = (tile / ntx) * 32, n0 = (tile % ntx) * 32;
    const int tx = threadIdx.x & 31, ty = threadIdx.x >> 5;   // 32 x 8
    #pragma unroll
    for (int i = 0; i < 32; i += 8)
      t[ty + i][tx] = S[(size_t)(k0 + ty + i) * N + n0 + tx];
    __syncthreads();
    #pragma unroll
    for (int i = 0; i < 32; i += 8)
      D[(size_t)(n0 + ty + i) * K + k0 + tx] = f2bf(t[tx][ty + i]);
    return;
  }
  // LN1 part
  const int wave = threadIdx.x >> 6, lane = threadIdx.x & 63;
  const int r = (bid - 736) * 4 + wave;
  if (r >= M_ROWS) return;
  const size_t base = (size_t)r * 256 + lane * 4;
  const float4 v = *reinterpret_cast<const float4*>(&x[base]);

  float lsum = v.x + v.y + v.z + v.w;
  #pragma unroll
  for (int m = 32; m; m >>= 1) lsum += __shfl_xor(lsum, m, 64);
  const float mean = lsum * (1.0f / 256.0f);

  const float dx = v.x - mean, dy = v.y - mean, dz = v.z - mean, dw = v.w - mean;
  float lsq = dx * dx + dy * dy + dz * dz + dw * dw;
  #pragma unroll
  for (int m = 32; m; m >>= 1) lsq += __shfl_xor(lsq, m, 64);
  const float rinv = rsqrtf(lsq * (1.0f / 256.0f) + 1e-5f);

  const float4 gg = *reinterpret_cast<const float4*>(&g[lane * 4]);
  const float4 bb = *reinterpret_cast<const float4*>(&bta[lane * 4]);
  const float o0 = dx * rinv * gg.x + bb.x;
  const float o1 = dy * rinv * gg.y + bb.y;
  const float o2 = dz * rinv * gg.z + bb.z;
  const float o3 = dw * rinv * gg.w + bb.w;
  ushort4 yo; yo.x = f2bf(o0); yo.y = f2bf(o1); yo.z = f2bf(o2); yo.w = f2bf(o3);
  *reinterpret_cast<ushort4*>(&y[base]) = yo;
  const float4 pp = *reinterpret_cast<const float4*>(&pos[base]);
  ushort4 qo;
  qo.x = f2bf(o0 + pp.x); qo.y = f2bf(o1 + pp.y);
  qo.z = f2bf(o2 + pp.z); qo.w = f2bf(o3 + pp.w);
  *reinterpret_cast<ushort4*>(&q[base]) = qo;
}

// ---------------------------------------------------------------------------
// BK=32 staging helper (for outln, 8KB slice).
// ---------------------------------------------------------------------------
template <int K>
__device__ __forceinline__ void stage64(
    const unsigned short* __restrict__ A, const unsigned short* __restrict__ Wt,
    unsigned short* As, unsigned short* Bs,
    int M, int row0, int col0, int k0, int lane) {
  #pragma unroll
  for (int i = 0; i < 4; ++i) {
    const int chunk = i * 64 + lane;
    const int rrow = chunk >> 2;
    const int kgs = (chunk & 3) ^ ((rrow >> 1) & 3);
    int ga = row0 + rrow; if (ga >= M) ga = M - 1;
    __builtin_amdgcn_global_load_lds(
        (const __attribute__((address_space(1))) void*)(A + (size_t)ga * K + k0 + kgs * 8),
        (__attribute__((address_space(3))) void*)(As + chunk * 8), 16, 0, 0);
  }
  #pragma unroll
  for (int i = 0; i < 4; ++i) {
    const int chunk = i * 64 + lane;
    const int rrow = chunk >> 2;
    const int kgs = (chunk & 3) ^ ((rrow >> 1) & 3);
    __builtin_amdgcn_global_load_lds(
        (const __attribute__((address_space(1))) void*)(Wt + (size_t)(col0 + rrow) * K + k0 + kgs * 8),
        (__attribute__((address_space(3))) void*)(Bs + chunk * 8), 16, 0, 0);
  }
}

// ---------------------------------------------------------------------------
// BK=64 staging: 64x64 bf16 A-tile + B-tile (8KB each). 8-slot XOR swizzle
// kg^(row&7); source pre-swizzled, LDS dest linear (rule 21).
// ---------------------------------------------------------------------------
template <int K>
__device__ __forceinline__ void stage64x64(
    const unsigned short* __restrict__ A, const unsigned short* __restrict__ Wt,
    unsigned short* As, unsigned short* Bs,
    int M, int row0, int col0, int k0, int lane) {
  #pragma unroll
  for (int i = 0; i < 8; ++i) {
    const int chunk = i * 64 + lane;     // 0..511
    const int rrow = chunk >> 3;         // 0..63
    const int kgs = (chunk & 7) ^ (rrow & 7);
    int ga = row0 + rrow; if (ga >= M) ga = M - 1;
    __builtin_amdgcn_global_load_lds(
        (const __attribute__((address_space(1))) void*)(A + (size_t)ga * K + k0 + kgs * 8),
        (__attribute__((address_space(3))) void*)(As + chunk * 8), 16, 0, 0);
  }
  #pragma unroll
  for (int i = 0; i < 8; ++i) {
    const int chunk = i * 64 + lane;
    const int rrow = chunk >> 3;
    const int kgs = (chunk & 7) ^ (rrow & 7);
    __builtin_amdgcn_global_load_lds(
        (const __attribute__((address_space(1))) void*)(Wt + (size_t)(col0 + rrow) * K + k0 + kgs * 8),
        (__attribute__((address_space(3))) void*)(Bs + chunk * 8), 16, 0, 0);
  }
}

// ---------------------------------------------------------------------------
// GEMM epilogue (shared). EPI: 0=bias->bf16, 1=bias+relu->bf16,
// 2=bias+res(f32)->f32, 3=split bf16, 4=bias+res(bf16)->f32.
// ---------------------------------------------------------------------------
template <int EPI, bool OUTBF>
__device__ __forceinline__ void gemm_epilogue(
    f32x4 (&acc)[4][4], const float* __restrict__ bias, const float* __restrict__ R,
    void* __restrict__ Cv, void* __restrict__ Cv2,
    int M, int N, int row0, int col0, int lane) {
  const int lr = lane & 15;
  const int cb = (lane >> 4) * 4;
  #pragma unroll
  for (int mi = 0; mi < 4; ++mi) {
    const int grow = row0 + mi * 16 + lr;
    if (grow >= M) continue;
    #pragma unroll
    for (int ni = 0; ni < 4; ++ni) {
      const int gcol = col0 + ni * 16 + cb;
      float4 b4;
      if (EPI == 3) b4 = (gcol < 256) ? *reinterpret_cast<const float4*>(&bias[gcol])
                                      : *reinterpret_cast<const float4*>(&R[gcol - 256]);
      else          b4 = *reinterpret_cast<const float4*>(&bias[gcol]);
      float v0 = acc[mi][ni][0] + b4.x;
      float v1 = acc[mi][ni][1] + b4.y;
      float v2 = acc[mi][ni][2] + b4.z;
      float v3 = acc[mi][ni][3] + b4.w;
      if (EPI == 1) {
        v0 = fmaxf(v0, 0.f); v1 = fmaxf(v1, 0.f);
        v2 = fmaxf(v2, 0.f); v3 = fmaxf(v3, 0.f);
      }
      if (EPI == 2) {
        const float4 r4 = *reinterpret_cast<const float4*>(&R[(size_t)grow * N + gcol]);
        v0 += r4.x; v1 += r4.y; v2 += r4.z; v3 += r4.w;
        float4 o; o.x = v0; o.y = v1; o.z = v2; o.w = v3;
        *reinterpret_cast<float4*>(&((float*)Cv)[(size_t)grow * N + gcol]) = o;
      } else if (EPI == 4) {
        const unsigned short* Rb = (const unsigned short*)R;
        const ushort4 r4 = *reinterpret_cast<const ushort4*>(&Rb[(size_t)grow * N + gcol]);
        v0 += bf2f(r4.x); v1 += bf2f(r4.y); v2 += bf2f(r4.z); v3 += bf2f(r4.w);
        float4 o; o.x = v0; o.y = v1; o.z = v2; o.w = v3;
        *reinterpret_cast<float4*>(&((float*)Cv)[(size_t)grow * N + gcol]) = o;
      } else {
        ushort4 o;
        o.x = f2bf(v0); o.y = f2bf(v1); o.z = f2bf(v2); o.w = f2bf(v3);
        if (EPI == 3) {
          if (gcol < 256)
            *reinterpret_cast<ushort4*>(&((unsigned short*)Cv )[(size_t)grow * 256 + gcol]) = o;
          else
            *reinterpret_cast<ushort4*>(&((unsigned short*)Cv2)[(size_t)grow * 128 + gcol - 256]) = o;
        } else {
          *reinterpret_cast<ushort4*>(&((unsigned short*)Cv)[(size_t)grow * N + gcol]) = o;
        }
      }
    }
  }
}

// ---------------------------------------------------------------------------
// BK=64 per-wave GEMM core (1 wave/block, 16KB LDS), two-half schedule.
// ---------------------------------------------------------------------------
template <int EPI, bool OUTBF, int K>
__device__ __forceinline__ void wgemm64_core(
    const unsigned short* __restrict__ A, const unsigned short* __restrict__ Wt,
    const float* __restrict__ bias, const float* __restrict__ R,
    void* __restrict__ Cv, void* __restrict__ Cv2,
    int M, int N, int row0, int col0, unsigned short* lds) {
  const int lane = threadIdx.x & 63;
  unsigned short* As = lds;             // 64x64 bf16 = 8KB
  unsigned short* Bs = lds + 64 * 64;   // 64x64 bf16 = 8KB

  f32x4 acc[4][4] = {};
  const int frow = lane & 15;
  const int gsel = lane >> 4;           // 0..3

  stage64x64<K>(A, Wt, As, Bs, M, row0, col0, 0, lane);
  asm volatile("s_waitcnt vmcnt(0)" ::: "memory");

  #pragma unroll
  for (int k0 = 0; k0 < K; k0 += 64) {
    // half 0
    short8 a0[4], b0[4];
    #pragma unroll
    for (int mi = 0; mi < 4; ++mi) {
      const int r = mi * 16 + frow;
      a0[mi] = *reinterpret_cast<const short8*>(&As[r * 64 + ((gsel ^ (r & 7)) * 8)]);
    }
    #pragma unroll
    for (int ni = 0; ni < 4; ++ni) {
      const int r = ni * 16 + frow;
      b0[ni] = *reinterpret_cast<const short8*>(&Bs[r * 64 + ((gsel ^ (r & 7)) * 8)]);
    }
    #pragma unroll
    for (int mi = 0; mi < 4; ++mi)
      #pragma unroll
      for (int ni = 0; ni < 4; ++ni)
        acc[mi][ni] = __builtin_amdgcn_mfma_f32_16x16x32_bf16(b0[ni], a0[mi], acc[mi][ni], 0, 0, 0);

    // half 1
    short8 a1[4], b1[4];
    #pragma unroll
    for (int mi = 0; mi < 4; ++mi) {
      const int r = mi * 16 + frow;
      a1[mi] = *reinterpret_cast<const short8*>(&As[r * 64 + (((4 + gsel) ^ (r & 7)) * 8)]);
    }
    #pragma unroll
    for (int ni = 0; ni < 4; ++ni) {
      const int r = ni * 16 + frow;
      b1[ni] = *reinterpret_cast<const short8*>(&Bs[r * 64 + (((4 + gsel) ^ (r & 7)) * 8)]);
    }
    asm volatile("s_waitcnt lgkmcnt(0)" ::: "memory");
    __builtin_amdgcn_sched_barrier(0);

    if (k0 + 64 < K)
      stage64x64<K>(A, Wt, As, Bs, M, row0, col0, k0 + 64, lane);

    #pragma unroll
    for (int mi = 0; mi < 4; ++mi)
      #pragma unroll
      for (int ni = 0; ni < 4; ++ni)
        acc[mi][ni] = __builtin_amdgcn_mfma_f32_16x16x32_bf16(b1[ni], a1[mi], acc[mi][ni], 0, 0, 0);

    if (k0 + 64 < K)
      asm volatile("s_waitcnt vmcnt(0)" ::: "memory");
  }

  gemm_epilogue<EPI, OUTBF>(acc, bias, R, Cv, Cv2, M, N, row0, col0, lane);
}

template <int EPI, bool OUTBF, int K>
__global__ __launch_bounds__(64) void wgemm64_k(
    const unsigned short* __restrict__ A, const unsigned short* __restrict__ Wt,
    const float* __restrict__ bias, const float* __restrict__ R,
    void* __restrict__ Cv, int M, int N) {
  __shared__ unsigned short lds[2 * 64 * 64];   // 16KB
  const int nwg = gridDim.x;
  const int bid = blockIdx.x;
  const int wgid = (bid & 7) * (nwg >> 3) + (bid >> 3);   // XCD chunk swizzle
  const int CT = N >> 6;
  const int row0 = (wgid / CT) * 64;
  const int col0 = (wgid % CT) * 64;
  wgemm64_core<EPI, OUTBF, K>(A, Wt, bias, R, Cv, nullptr, M, N, row0, col0, lds);
}

// value proj (1664 tiles) + off/attn proj (2496 tiles), 4160 one-wave blocks
__global__ __launch_bounds__(64) void wproj64_fused(
    const unsigned short* __restrict__ srcn, const unsigned short* __restrict__ q,
    const unsigned short* __restrict__ wt_val, const unsigned short* __restrict__ wt_offattn,
    const float* __restrict__ b_value, const float* __restrict__ b_off,
    const float* __restrict__ b_attn,
    unsigned short* __restrict__ vout, unsigned short* __restrict__ offout,
    unsigned short* __restrict__ awout, int M) {
  __shared__ unsigned short lds[2 * 64 * 64];
  const int nwg = gridDim.x;     // 4160
  const int bid = blockIdx.x;
  const int tile = (bid & 7) * (nwg >> 3) + (bid >> 3);
  if (tile < 1664) {
    const int row0 = (tile >> 2) * 64, col0 = (tile & 3) * 64;
    wgemm64_core<0, true, 256>(srcn, wt_val, b_value, nullptr, vout, nullptr,
                               M, 256, row0, col0, lds);
  } else {
    const int t2 = tile - 1664;
    const int row0 = (t2 / 6) * 64, col0 = (t2 % 6) * 64;
    wgemm64_core<3, false, 256>(q, wt_offattn, b_off, b_attn, offout, awout,
                                M, 384, row0, col0, lds);
  }
}

// ---------------------------------------------------------------------------
// out-proj + residual + FUSED LayerNorm2 (256-thread, BK=32).
// ---------------------------------------------------------------------------
__global__ __launch_bounds__(256, 3) void outln_kernel(
    const unsigned short* __restrict__ attn, const unsigned short* __restrict__ wt_out,
    const float* __restrict__ b_out, const float* __restrict__ src,
    const float* __restrict__ ln_g, const float* __restrict__ ln_b,
    unsigned short* __restrict__ src1, unsigned short* __restrict__ sn2, int M) {
  __shared__ unsigned short lds[4 * 4096];
  __shared__ float s_sum[64][4];
  __shared__ float s_sq[64][4];
  const int w = threadIdx.x >> 6, lane = threadIdx.x & 63;
  const int nwg = gridDim.x;    // 416
  const int bid = blockIdx.x;
  const int wgid = (bid & 7) * (nwg >> 3) + (bid >> 3);
  const int row0 = wgid * 64;
  const int col0 = w * 64;
  unsigned short* As = lds + w * 4096;
  unsigned short* Bs = As + 64 * 32;

  f32x4 acc[4][4] = {};
  const int frow = lane & 15;
  const int fke = ((lane >> 4) ^ ((frow >> 1) & 3)) * 8;

  stage64<256>(attn, wt_out, As, Bs, M, row0, col0, 0, lane);
  asm volatile("s_waitcnt vmcnt(0)" ::: "memory");
  #pragma unroll
  for (int k0 = 0; k0 < 256; k0 += 32) {
    short8 a[4], b[4];
    #pragma unroll
    for (int mi = 0; mi < 4; ++mi)
      a[mi] = *reinterpret_cast<const short8*>(&As[(mi * 16 + frow) * 32 + fke]);
    #pragma unroll
    for (int ni = 0; ni < 4; ++ni)
      b[ni] = *reinterpret_cast<const short8*>(&Bs[(ni * 16 + frow) * 32 + fke]);
    asm volatile("s_waitcnt lgkmcnt(0)" ::: "memory");
    __builtin_amdgcn_sched_barrier(0);
    if (k0 + 32 < 256)
      stage64<256>(attn, wt_out, As, Bs, M, row0, col0, k0 + 32, lane);
    #pragma unroll
    for (int mi = 0; mi < 4; ++mi)
      #pragma unroll
      for (int ni = 0; ni < 4; ++ni)
        acc[mi][ni] = __builtin_amdgcn_mfma_f32_16x16x32_bf16(b[ni], a[mi], acc[mi][ni], 0, 0, 0);
    if (k0 + 32 < 256)
      asm volatile("s_waitcnt vmcnt(0)" ::: "memory");
  }

  const int lr = lane & 15;
  const int cb = (lane >> 4) * 4;
  float lsum[4], lsq[4];
  #pragma unroll
  for (int mi = 0; mi < 4; ++mi) {
    const int grow = row0 + mi * 16 + lr;
    const bool ok = grow < M;
    float rs = 0.f, rq = 0.f;
    #pragma unroll
    for (int ni = 0; ni < 4; ++ni) {
      const int gcol = col0 + ni * 16 + cb;
      const float4 b4 = *reinterpret_cast<const float4*>(&b_out[gcol]);
      float4 r4 = make_float4(0.f, 0.f, 0.f, 0.f);
      if (ok) r4 = *reinterpret_cast<const float4*>(&src[(size_t)grow * 256 + gcol]);
      float v0 = acc[mi][ni][0] + b4.x + r4.x;
      float v1 = acc[mi][ni][1] + b4.y + r4.y;
      float v2 = acc[mi][ni][2] + b4.z + r4.z;
      float v3 = acc[mi][ni][3] + b4.w + r4.w;
      acc[mi][ni][0] = v0; acc[mi][ni][1] = v1;
      acc[mi][ni][2] = v2; acc[mi][ni][3] = v3;
      if (ok) {
        ushort4 o;
        o.x = f2bf(v0); o.y = f2bf(v1); o.z = f2bf(v2); o.w = f2bf(v3);
        *reinterpret_cast<ushort4*>(&src1[(size_t)grow * 256 + gcol]) = o;
      }
      rs += v0 + v1 + v2 + v3;
      rq += v0 * v0 + v1 * v1 + v2 * v2 + v3 * v3;
    }
    lsum[mi] = rs; lsq[mi] = rq;
  }
  #pragma unroll
  for (int mi = 0; mi < 4; ++mi) {
    lsum[mi] += __shfl_xor(lsum[mi], 16, 64);
    lsum[mi] += __shfl_xor(lsum[mi], 32, 64);
    lsq[mi]  += __shfl_xor(lsq[mi], 16, 64);
    lsq[mi]  += __shfl_xor(lsq[mi], 32, 64);
  }
  if (lane < 16) {
    #pragma unroll
    for (int mi = 0; mi < 4; ++mi) {
      s_sum[mi * 16 + lane][w] = lsum[mi];
      s_sq[mi * 16 + lane][w] = lsq[mi];
    }
  }
  __syncthreads();
  #pragma unroll
  for (int mi = 0; mi < 4; ++mi) {
    const int lrow = mi * 16 + lr;
    const int grow = row0 + lrow;
    if (grow >= M) continue;
    const float ssum = s_sum[lrow][0] + s_sum[lrow][1] + s_sum[lrow][2] + s_sum[lrow][3];
    const float ssq = s_sq[lrow][0] + s_sq[lrow][1] + s_sq[lrow][2] + s_sq[lrow][3];
    const float mean = ssum * (1.0f / 256.0f);
    const float var = ssq * (1.0f / 256.0f) - mean * mean;
    const float rinv = rsqrtf(var + 1e-5f);
    #pragma unroll
    for (int ni = 0; ni < 4; ++ni) {
      const int gcol = col0 + ni * 16 + cb;
      const float4 g4 = *reinterpret_cast<const float4*>(&ln_g[gcol]);
      const float4 bb = *reinterpret_cast<const float4*>(&ln_b[gcol]);
      ushort4 o;
      o.x = f2bf((acc[mi][ni][0] - mean) * rinv * g4.x + bb.x);
      o.y = f2bf((acc[mi][ni][1] - mean) * rinv * g4.y + bb.y);
      o.z = f2bf((acc[mi][ni][2] - mean) * rinv * g4.z + bb.z);
      o.w = f2bf((acc[mi][ni][3] - mean) * rinv * g4.w + bb.w);
      *reinterpret_cast<ushort4*>(&sn2[(size_t)grow * 256 + gcol]) = o;
    }
  }
}

// ---------------------------------------------------------------------------
// Fused softmax + deformable sampling. Gather loop unroll 8 -> 16: doubles
// loads in flight per thread (MLP). VGPR headroom is free: LDS caps blocks
// at 4/CU (16 waves), so up to ~128 VGPR costs nothing (R17: more WAVES
// hurt via cache congestion; more in-flight loads per wave do not add waves).
// ---------------------------------------------------------------------------
__global__ __launch_bounds__(256) void msda_kernel(
    const unsigned short* __restrict__ v, const unsigned short* __restrict__ offb,
    const unsigned short* __restrict__ awl, const float* __restrict__ ref,
    unsigned short* __restrict__ outb) {
  const int r0 = blockIdx.x * 8;
  const int tid = threadIdx.x;

  __shared__ float s_aw[8 * 128];
  __shared__ float s_ref[64];
  __shared__ float2 s_wi[64 * 66];   // group stride 66 (bank pad)

  if (tid < 64) {
    int rr = r0 + (tid >> 3); if (rr >= M_ROWS) rr = M_ROWS - 1;
    s_ref[tid] = ref[(size_t)rr * 8 + (tid & 7)];
  }

  {
    const int g = tid >> 2, j = tid & 3;
    const int tok = g >> 3, h = g & 7;
    int rr = r0 + tok; if (rr >= M_ROWS) rr = M_ROWS - 1;
    const uint2 u = *reinterpret_cast<const uint2*>(&awl[(size_t)rr * 128 + h * 16 + j * 4]);
    const float l0 = bf2f((unsigned short)(u.x & 0xffff));
    const float l1 = bf2f((unsigned short)(u.x >> 16));
    const float l2 = bf2f((unsigned short)(u.y & 0xffff));
    const float l3 = bf2f((unsigned short)(u.y >> 16));
    float mx = fmaxf(fmaxf(l0, l1), fmaxf(l2, l3));
    mx = fmaxf(mx, __shfl_xor(mx, 1, 64));
    mx = fmaxf(mx, __shfl_xor(mx, 2, 64));
    const float e0 = expf(l0 - mx), e1 = expf(l1 - mx);
    const float e2 = expf(l2 - mx), e3 = expf(l3 - mx);
    float ss = e0 + e1 + e2 + e3;
    ss += __shfl_xor(ss, 1, 64);
    ss += __shfl_xor(ss, 2, 64);
    const float inv = 1.0f / ss;
    float4 w4; w4.x = e0 * inv; w4.y = e1 * inv; w4.z = e2 * inv; w4.w = e3 * inv;
    *reinterpret_cast<float4*>(&s_aw[g * 16 + j * 4]) = w4;
  }
  __syncthreads();

  const int HH[4] = {100, 50, 25, 13};
  const int WW[4] = {100, 50, 25, 13};
  const int SS[4] = {0, 10000, 12500, 13125};

  {
    const int pi0 = tid * 4;
    const int tok = pi0 >> 7, h = (pi0 >> 4) & 7;
    const int g = pi0 >> 4;
    const int pt0 = pi0 & 15;
    const int l = pt0 >> 2;
    int rr = r0 + tok; if (rr >= M_ROWS) rr = M_ROWS - 1;
    const float Wl = (float)WW[l], Hl = (float)HH[l];
    const float rx = s_ref[tok * 8 + l * 2], ry = s_ref[tok * 8 + l * 2 + 1];
    const uint4 uoff = *reinterpret_cast<const uint4*>(&offb[(size_t)rr * 256 + h * 32 + pt0 * 2]);
    const float4 aw4 = *reinterpret_cast<const float4*>(&s_aw[g * 16 + pt0]);
    const unsigned int uo[4] = {uoff.x, uoff.y, uoff.z, uoff.w};
    const float awv[4] = {aw4.x, aw4.y, aw4.z, aw4.w};
    #pragma unroll
    for (int p = 0; p < 4; ++p) {
      const float ox = bf2f((unsigned short)(uo[p] & 0xffff));
      const float oy = bf2f((unsigned short)(uo[p] >> 16));
      const float x = rx * Wl + ox - 0.5f;
      const float y = ry * Hl + oy - 0.5f;
      const float x0f = floorf(x), y0f = floorf(y);
      const int x0 = (int)x0f, y0 = (int)y0f;
      const float wx1 = x - x0f, wy1 = y - y0f;
      const float wx0 = 1.f - wx1, wy0 = 1.f - wy1;
      const float aw = awv[p];
      #pragma unroll
      for (int c = 0; c < 4; ++c) {
        const int xx = x0 + (c & 1), yy = y0 + (c >> 1);
        const bool valid = (xx >= 0) & (xx < WW[l]) & (yy >= 0) & (yy < HH[l]);
        const int xc = min(max(xx, 0), WW[l] - 1);
        const int yc = min(max(yy, 0), HH[l] - 1);
        float wgt = aw * ((c & 1) ? wx1 : wx0) * ((c >> 1) ? wy1 : wy0);
        wgt = valid ? wgt : 0.f;
        const int idxb = (SS[l] + yc * WW[l] + xc) * 512;
        s_wi[g * 66 + (pt0 + p) * 4 + c] = make_float2(wgt, __int_as_float(idxb));
      }
    }
  }
  __syncthreads();

  const int tok = tid >> 5;
  const int h = (tid >> 2) & 7;
  const int d8 = tid & 3;
  const int r = r0 + tok;
  const int rc = (r < M_ROWS) ? r : M_ROWS - 1;
  const int b = rc / T_TOK;
  const char* vb = (const char*)(v + (size_t)b * T_TOK * 256 + h * 32 + d8 * 8);
  const int e0 = (tok * 8 + h) * 66;

  float a0 = 0.f, a1 = 0.f, a2 = 0.f, a3 = 0.f;
  float a4 = 0.f, a5 = 0.f, a6 = 0.f, a7 = 0.f;
  #pragma unroll 16
  for (int j = 0; j < 64; ++j) {
    const float2 wi = s_wi[e0 + j];
    const float wgt = wi.x;
    const int idxb = __float_as_int(wi.y);
    const uint4 u = *reinterpret_cast<const uint4*>(vb + idxb);
    a0 = fmaf(wgt, bf2f((unsigned short)(u.x & 0xffff)), a0);
    a1 = fmaf(wgt, bf2f((unsigned short)(u.x >> 16)), a1);
    a2 = fmaf(wgt, bf2f((unsigned short)(u.y & 0xffff)), a2);
    a3 = fmaf(wgt, bf2f((unsigned short)(u.y >> 16)), a3);
    a4 = fmaf(wgt, bf2f((unsigned short)(u.z & 0xffff)), a4);
    a5 = fmaf(wgt, bf2f((unsigned short)(u.z >> 16)), a5);
    a6 = fmaf(wgt, bf2f((unsigned short)(u.w & 0xffff)), a6);
    a7 = fmaf(wgt, bf2f((unsigned short)(u.w >> 16)), a7);
  }
  if (r < M_ROWS) {
    uint4 o;
    o.x = ((unsigned int)f2bf(a0)) | ((unsigned int)f2bf(a1) << 16);
    o.y = ((unsigned int)f2bf(a2)) | ((unsigned int)f2bf(a3) << 16);
    o.z = ((unsigned int)f2bf(a4)) | ((unsigned int)f2bf(a5) << 16);
    o.w = ((unsigned int)f2bf(a6)) | ((unsigned int)f2bf(a7) << 16);
    *reinterpret_cast<uint4*>(&outb[(size_t)r * 256 + h * 32 + d8 * 8]) = o;
  }
}

// ---------------------------------------------------------------------------
// Host launcher
// ---------------------------------------------------------------------------
extern "C" void kernel_launch(void* const* d_in, const int* in_sizes, int n_in,
                              void* d_out, int out_size, void* d_ws, size_t ws_size,
                              hipStream_t stream) {
  const float* src     = (const float*)d_in[0];
  const float* pos     = (const float*)d_in[1];
  const float* ref     = (const float*)d_in[2];
  const float* ln1_g   = (const float*)d_in[5];
  const float* ln1_b   = (const float*)d_in[6];
  const float* ln2_g   = (const float*)d_in[7];
  const float* ln2_b   = (const float*)d_in[8];
  const float* W_value = (const float*)d_in[9];
  const float* b_value = (const float*)d_in[10];
  const float* W_off   = (const float*)d_in[11];
  const float* b_off   = (const float*)d_in[12];
  const float* W_attn  = (const float*)d_in[13];
  const float* b_attn  = (const float*)d_in[14];
  const float* W_out   = (const float*)d_in[15];
  const float* b_out   = (const float*)d_in[16];
  const float* W_ffn1  = (const float*)d_in[17];
  const float* b_ffn1  = (const float*)d_in[18];
  const float* W_ffn2  = (const float*)d_in[19];
  const float* b_ffn2  = (const float*)d_in[20];
  float* out = (float*)d_out;

  const int M = M_ROWS;
  const size_t n256 = (size_t)M * 256;

  // workspace layout
  unsigned short* src_n_bf = (unsigned short*)d_ws;
  unsigned short* q_bf     = src_n_bf + n256;
  unsigned short* v_bf     = q_bf + n256;
  unsigned short* attn_bf  = v_bf + n256;
  unsigned short* sn2_bf   = attn_bf + n256;
  unsigned short* hid_bf   = sn2_bf + n256;                  // M*1024
  unsigned short* offb     = hid_bf + (size_t)M * 1024;      // M*256 bf16
  unsigned short* awbuf    = offb + n256;                    // M*128 bf16
  unsigned short* src1_bf  = awbuf + (size_t)M * 128;        // M*256 bf16
  unsigned short* wt_val     = src1_bf + n256;
  unsigned short* wt_offattn = wt_val + 256 * 256;            // [384,256]
  unsigned short* wt_out     = wt_offattn + 384 * 256;
  unsigned short* wt_ffn1    = wt_out + 256 * 256;
  unsigned short* wt_ffn2    = wt_ffn1 + 1024 * 256;

  // 0+1. weight transposes + LN1 fused
  prep_kernel<<<736 + (M + 3) / 4, 256, 0, stream>>>(
      W_value, W_off, W_attn, W_out, W_ffn1, W_ffn2,
      wt_val, wt_offattn, wt_offattn + 256 * 256, wt_out, wt_ffn1, wt_ffn2,
      src, pos, ln1_g, ln1_b, src_n_bf, q_bf);

  // 2. value proj + off/attn proj: 4160 one-wave blocks (BK=64)
  wproj64_fused<<<4160, 64, 0, stream>>>(
      src_n_bf, q_bf, wt_val, wt_offattn, b_value, b_off, b_attn,
      v_bf, offb, awbuf, M);

  // 3. softmax + sampling (8 tokens/block)
  msda_kernel<<<(M + 7) / 8, 256, 0, stream>>>(v_bf, offb, awbuf, ref, attn_bf);

  // 4. out-proj + residual + LN2 fused -> src1 (bf16) + sn2 (bf16)
  outln_kernel<<<416, 256, 0, stream>>>(attn_bf, wt_out, b_out, src,
                                        ln2_g, ln2_b, src1_bf, sn2_bf, M);

  // 5. FFN (BK=64 one-wave blocks; ffn2 residual = bf16 src1, EPI 4)
  wgemm64_k<1, true, 256 ><<<6656, 64, 0, stream>>>(sn2_bf, wt_ffn1, b_ffn1, nullptr,
                                                    hid_bf, M, 1024);
  wgemm64_k<4, false, 1024><<<1664, 64, 0, stream>>>(hid_bf, wt_ffn2, b_ffn2,
                                                     (const float*)src1_bf,
                                                     out, M, 256);
}

// Round 22
// 174.778 us; speedup vs baseline: 1.1863x; 1.1863x over previous
//
#include <hip/hip_runtime.h>
#include <hip/hip_bf16.h>

#define T_TOK   13294
#define BS_     2
#define M_ROWS  (BS_ * T_TOK)   // 26588
#define EMBED_  256
#define HID_    1024

typedef __attribute__((ext_vector_type(8))) short short8;
typedef __attribute__((ext_vector_type(4))) float f32x4;

__device__ __forceinline__ unsigned short f2bf(float f) {
  __hip_bfloat16 h = __float2bfloat16(f);
  return *reinterpret_cast<unsigned short*>(&h);
}
__device__ __forceinline__ float bf2f(unsigned short u) {
  unsigned int x = ((unsigned int)u) << 16;
  return __uint_as_float(x);
}

// ---------------------------------------------------------------------------
// Fused prep: blocks 0..735 = weight transpose+bf16; rest = LN1 (+pos).
// ---------------------------------------------------------------------------
__global__ __launch_bounds__(256) void prep_kernel(
    const float* __restrict__ s0, const float* __restrict__ s1,
    const float* __restrict__ s2, const float* __restrict__ s3,
    const float* __restrict__ s4, const float* __restrict__ s5,
    unsigned short* __restrict__ d0, unsigned short* __restrict__ d1,
    unsigned short* __restrict__ d2, unsigned short* __restrict__ d3,
    unsigned short* __restrict__ d4, unsigned short* __restrict__ d5,
    const float* __restrict__ x, const float* __restrict__ pos,
    const float* __restrict__ g, const float* __restrict__ bta,
    unsigned short* __restrict__ y, unsigned short* __restrict__ q) {
  const int bid = blockIdx.x;
  if (bid < 736) {
    __shared__ float t[32][33];
    const float* S; unsigned short* D; int K, N, t0;
    if      (bid <  64) { S = s0; D = d0; K = 256;  N = 256;  t0 = 0;   }
    else if (bid < 128) { S = s1; D = d1; K = 256;  N = 256;  t0 = 64;  }
    else if (bid < 160) { S = s2; D = d2; K = 256;  N = 128;  t0 = 128; }
    else if (bid < 224) { S = s3; D = d3; K = 256;  N = 256;  t0 = 160; }
    else if (bid < 480) { S = s4; D = d4; K = 256;  N = 1024; t0 = 224; }
    else                { S = s5; D = d5; K = 1024; N = 256;  t0 = 480; }
    const int tile = bid - t0;
    const int ntx = N >> 5;
    const int k0 = (tile / ntx) * 32, n0 = (tile % ntx) * 32;
    const int tx = threadIdx.x & 31, ty = threadIdx.x >> 5;   // 32 x 8
    #pragma unroll
    for (int i = 0; i < 32; i += 8)
      t[ty + i][tx] = S[(size_t)(k0 + ty + i) * N + n0 + tx];
    __syncthreads();
    #pragma unroll
    for (int i = 0; i < 32; i += 8)
      D[(size_t)(n0 + ty + i) * K + k0 + tx] = f2bf(t[tx][ty + i]);
    return;
  }
  // LN1 part
  const int wave = threadIdx.x >> 6, lane = threadIdx.x & 63;
  const int r = (bid - 736) * 4 + wave;
  if (r >= M_ROWS) return;
  const size_t base = (size_t)r * 256 + lane * 4;
  const float4 v = *reinterpret_cast<const float4*>(&x[base]);

  float lsum = v.x + v.y + v.z + v.w;
  #pragma unroll
  for (int m = 32; m; m >>= 1) lsum += __shfl_xor(lsum, m, 64);
  const float mean = lsum * (1.0f / 256.0f);

  const float dx = v.x - mean, dy = v.y - mean, dz = v.z - mean, dw = v.w - mean;
  float lsq = dx * dx + dy * dy + dz * dz + dw * dw;
  #pragma unroll
  for (int m = 32; m; m >>= 1) lsq += __shfl_xor(lsq, m, 64);
  const float rinv = rsqrtf(lsq * (1.0f / 256.0f) + 1e-5f);

  const float4 gg = *reinterpret_cast<const float4*>(&g[lane * 4]);
  const float4 bb = *reinterpret_cast<const float4*>(&bta[lane * 4]);
  const float o0 = dx * rinv * gg.x + bb.x;
  const float o1 = dy * rinv * gg.y + bb.y;
  const float o2 = dz * rinv * gg.z + bb.z;
  const float o3 = dw * rinv * gg.w + bb.w;
  ushort4 yo; yo.x = f2bf(o0); yo.y = f2bf(o1); yo.z = f2bf(o2); yo.w = f2bf(o3);
  *reinterpret_cast<ushort4*>(&y[base]) = yo;
  const float4 pp = *reinterpret_cast<const float4*>(&pos[base]);
  ushort4 qo;
  qo.x = f2bf(o0 + pp.x); qo.y = f2bf(o1 + pp.y);
  qo.z = f2bf(o2 + pp.z); qo.w = f2bf(o3 + pp.w);
  *reinterpret_cast<ushort4*>(&q[base]) = qo;
}

// ---------------------------------------------------------------------------
// BK=32 staging helper (for outln, 8KB slice).
// ---------------------------------------------------------------------------
template <int K>
__device__ __forceinline__ void stage64(
    const unsigned short* __restrict__ A, const unsigned short* __restrict__ Wt,
    unsigned short* As, unsigned short* Bs,
    int M, int row0, int col0, int k0, int lane) {
  #pragma unroll
  for (int i = 0; i < 4; ++i) {
    const int chunk = i * 64 + lane;
    const int rrow = chunk >> 2;
    const int kgs = (chunk & 3) ^ ((rrow >> 1) & 3);
    int ga = row0 + rrow; if (ga >= M) ga = M - 1;
    __builtin_amdgcn_global_load_lds(
        (const __attribute__((address_space(1))) void*)(A + (size_t)ga * K + k0 + kgs * 8),
        (__attribute__((address_space(3))) void*)(As + chunk * 8), 16, 0, 0);
  }
  #pragma unroll
  for (int i = 0; i < 4; ++i) {
    const int chunk = i * 64 + lane;
    const int rrow = chunk >> 2;
    const int kgs = (chunk & 3) ^ ((rrow >> 1) & 3);
    __builtin_amdgcn_global_load_lds(
        (const __attribute__((address_space(1))) void*)(Wt + (size_t)(col0 + rrow) * K + k0 + kgs * 8),
        (__attribute__((address_space(3))) void*)(Bs + chunk * 8), 16, 0, 0);
  }
}

// ---------------------------------------------------------------------------
// BK=64 staging: 64x64 bf16 A-tile + B-tile (8KB each). 8-slot XOR swizzle
// kg^(row&7); source pre-swizzled, LDS dest linear (rule 21).
// ---------------------------------------------------------------------------
template <int K>
__device__ __forceinline__ void stage64x64(
    const unsigned short* __restrict__ A, const unsigned short* __restrict__ Wt,
    unsigned short* As, unsigned short* Bs,
    int M, int row0, int col0, int k0, int lane) {
  #pragma unroll
  for (int i = 0; i < 8; ++i) {
    const int chunk = i * 64 + lane;     // 0..511
    const int rrow = chunk >> 3;         // 0..63
    const int kgs = (chunk & 7) ^ (rrow & 7);
    int ga = row0 + rrow; if (ga >= M) ga = M - 1;
    __builtin_amdgcn_global_load_lds(
        (const __attribute__((address_space(1))) void*)(A + (size_t)ga * K + k0 + kgs * 8),
        (__attribute__((address_space(3))) void*)(As + chunk * 8), 16, 0, 0);
  }
  #pragma unroll
  for (int i = 0; i < 8; ++i) {
    const int chunk = i * 64 + lane;
    const int rrow = chunk >> 3;
    const int kgs = (chunk & 7) ^ (rrow & 7);
    __builtin_amdgcn_global_load_lds(
        (const __attribute__((address_space(1))) void*)(Wt + (size_t)(col0 + rrow) * K + k0 + kgs * 8),
        (__attribute__((address_space(3))) void*)(Bs + chunk * 8), 16, 0, 0);
  }
}

// ---------------------------------------------------------------------------
// GEMM epilogue (shared). EPI: 0=bias->bf16, 1=bias+relu->bf16,
// 2=bias+res(f32)->f32, 3=split bf16, 4=bias+res(bf16)->f32.
// ---------------------------------------------------------------------------
template <int EPI, bool OUTBF>
__device__ __forceinline__ void gemm_epilogue(
    f32x4 (&acc)[4][4], const float* __restrict__ bias, const float* __restrict__ R,
    void* __restrict__ Cv, void* __restrict__ Cv2,
    int M, int N, int row0, int col0, int lane) {
  const int lr = lane & 15;
  const int cb = (lane >> 4) * 4;
  #pragma unroll
  for (int mi = 0; mi < 4; ++mi) {
    const int grow = row0 + mi * 16 + lr;
    if (grow >= M) continue;
    #pragma unroll
    for (int ni = 0; ni < 4; ++ni) {
      const int gcol = col0 + ni * 16 + cb;
      float4 b4;
      if (EPI == 3) b4 = (gcol < 256) ? *reinterpret_cast<const float4*>(&bias[gcol])
                                      : *reinterpret_cast<const float4*>(&R[gcol - 256]);
      else          b4 = *reinterpret_cast<const float4*>(&bias[gcol]);
      float v0 = acc[mi][ni][0] + b4.x;
      float v1 = acc[mi][ni][1] + b4.y;
      float v2 = acc[mi][ni][2] + b4.z;
      float v3 = acc[mi][ni][3] + b4.w;
      if (EPI == 1) {
        v0 = fmaxf(v0, 0.f); v1 = fmaxf(v1, 0.f);
        v2 = fmaxf(v2, 0.f); v3 = fmaxf(v3, 0.f);
      }
      if (EPI == 2) {
        const float4 r4 = *reinterpret_cast<const float4*>(&R[(size_t)grow * N + gcol]);
        v0 += r4.x; v1 += r4.y; v2 += r4.z; v3 += r4.w;
        float4 o; o.x = v0; o.y = v1; o.z = v2; o.w = v3;
        *reinterpret_cast<float4*>(&((float*)Cv)[(size_t)grow * N + gcol]) = o;
      } else if (EPI == 4) {
        const unsigned short* Rb = (const unsigned short*)R;
        const ushort4 r4 = *reinterpret_cast<const ushort4*>(&Rb[(size_t)grow * N + gcol]);
        v0 += bf2f(r4.x); v1 += bf2f(r4.y); v2 += bf2f(r4.z); v3 += bf2f(r4.w);
        float4 o; o.x = v0; o.y = v1; o.z = v2; o.w = v3;
        *reinterpret_cast<float4*>(&((float*)Cv)[(size_t)grow * N + gcol]) = o;
      } else {
        ushort4 o;
        o.x = f2bf(v0); o.y = f2bf(v1); o.z = f2bf(v2); o.w = f2bf(v3);
        if (EPI == 3) {
          if (gcol < 256)
            *reinterpret_cast<ushort4*>(&((unsigned short*)Cv )[(size_t)grow * 256 + gcol]) = o;
          else
            *reinterpret_cast<ushort4*>(&((unsigned short*)Cv2)[(size_t)grow * 128 + gcol - 256]) = o;
        } else {
          *reinterpret_cast<ushort4*>(&((unsigned short*)Cv)[(size_t)grow * N + gcol]) = o;
        }
      }
    }
  }
}

// ---------------------------------------------------------------------------
// BK=64 per-wave GEMM core (1 wave/block, 16KB LDS), two-half schedule.
// ---------------------------------------------------------------------------
template <int EPI, bool OUTBF, int K>
__device__ __forceinline__ void wgemm64_core(
    const unsigned short* __restrict__ A, const unsigned short* __restrict__ Wt,
    const float* __restrict__ bias, const float* __restrict__ R,
    void* __restrict__ Cv, void* __restrict__ Cv2,
    int M, int N, int row0, int col0, unsigned short* lds) {
  const int lane = threadIdx.x & 63;
  unsigned short* As = lds;             // 64x64 bf16 = 8KB
  unsigned short* Bs = lds + 64 * 64;   // 64x64 bf16 = 8KB

  f32x4 acc[4][4] = {};
  const int frow = lane & 15;
  const int gsel = lane >> 4;           // 0..3

  stage64x64<K>(A, Wt, As, Bs, M, row0, col0, 0, lane);
  asm volatile("s_waitcnt vmcnt(0)" ::: "memory");

  #pragma unroll
  for (int k0 = 0; k0 < K; k0 += 64) {
    // half 0
    short8 a0[4], b0[4];
    #pragma unroll
    for (int mi = 0; mi < 4; ++mi) {
      const int r = mi * 16 + frow;
      a0[mi] = *reinterpret_cast<const short8*>(&As[r * 64 + ((gsel ^ (r & 7)) * 8)]);
    }
    #pragma unroll
    for (int ni = 0; ni < 4; ++ni) {
      const int r = ni * 16 + frow;
      b0[ni] = *reinterpret_cast<const short8*>(&Bs[r * 64 + ((gsel ^ (r & 7)) * 8)]);
    }
    #pragma unroll
    for (int mi = 0; mi < 4; ++mi)
      #pragma unroll
      for (int ni = 0; ni < 4; ++ni)
        acc[mi][ni] = __builtin_amdgcn_mfma_f32_16x16x32_bf16(b0[ni], a0[mi], acc[mi][ni], 0, 0, 0);

    // half 1
    short8 a1[4], b1[4];
    #pragma unroll
    for (int mi = 0; mi < 4; ++mi) {
      const int r = mi * 16 + frow;
      a1[mi] = *reinterpret_cast<const short8*>(&As[r * 64 + (((4 + gsel) ^ (r & 7)) * 8)]);
    }
    #pragma unroll
    for (int ni = 0; ni < 4; ++ni) {
      const int r = ni * 16 + frow;
      b1[ni] = *reinterpret_cast<const short8*>(&Bs[r * 64 + (((4 + gsel) ^ (r & 7)) * 8)]);
    }
    asm volatile("s_waitcnt lgkmcnt(0)" ::: "memory");
    __builtin_amdgcn_sched_barrier(0);

    if (k0 + 64 < K)
      stage64x64<K>(A, Wt, As, Bs, M, row0, col0, k0 + 64, lane);

    #pragma unroll
    for (int mi = 0; mi < 4; ++mi)
      #pragma unroll
      for (int ni = 0; ni < 4; ++ni)
        acc[mi][ni] = __builtin_amdgcn_mfma_f32_16x16x32_bf16(b1[ni], a1[mi], acc[mi][ni], 0, 0, 0);

    if (k0 + 64 < K)
      asm volatile("s_waitcnt vmcnt(0)" ::: "memory");
  }

  gemm_epilogue<EPI, OUTBF>(acc, bias, R, Cv, Cv2, M, N, row0, col0, lane);
}

template <int EPI, bool OUTBF, int K>
__global__ __launch_bounds__(64) void wgemm64_k(
    const unsigned short* __restrict__ A, const unsigned short* __restrict__ Wt,
    const float* __restrict__ bias, const float* __restrict__ R,
    void* __restrict__ Cv, int M, int N) {
  __shared__ unsigned short lds[2 * 64 * 64];   // 16KB
  const int nwg = gridDim.x;
  const int bid = blockIdx.x;
  const int wgid = (bid & 7) * (nwg >> 3) + (bid >> 3);   // XCD chunk swizzle
  const int CT = N >> 6;
  const int row0 = (wgid / CT) * 64;
  const int col0 = (wgid % CT) * 64;
  wgemm64_core<EPI, OUTBF, K>(A, Wt, bias, R, Cv, nullptr, M, N, row0, col0, lds);
}

// value proj (1664 tiles) + off/attn proj (2496 tiles), 4160 one-wave blocks
__global__ __launch_bounds__(64) void wproj64_fused(
    const unsigned short* __restrict__ srcn, const unsigned short* __restrict__ q,
    const unsigned short* __restrict__ wt_val, const unsigned short* __restrict__ wt_offattn,
    const float* __restrict__ b_value, const float* __restrict__ b_off,
    const float* __restrict__ b_attn,
    unsigned short* __restrict__ vout, unsigned short* __restrict__ offout,
    unsigned short* __restrict__ awout, int M) {
  __shared__ unsigned short lds[2 * 64 * 64];
  const int nwg = gridDim.x;     // 4160
  const int bid = blockIdx.x;
  const int tile = (bid & 7) * (nwg >> 3) + (bid >> 3);
  if (tile < 1664) {
    const int row0 = (tile >> 2) * 64, col0 = (tile & 3) * 64;
    wgemm64_core<0, true, 256>(srcn, wt_val, b_value, nullptr, vout, nullptr,
                               M, 256, row0, col0, lds);
  } else {
    const int t2 = tile - 1664;
    const int row0 = (t2 / 6) * 64, col0 = (t2 % 6) * 64;
    wgemm64_core<3, false, 256>(q, wt_offattn, b_off, b_attn, offout, awout,
                                M, 384, row0, col0, lds);
  }
}

// ---------------------------------------------------------------------------
// out-proj + residual + FUSED LayerNorm2 (256-thread, BK=32).
// ---------------------------------------------------------------------------
__global__ __launch_bounds__(256, 3) void outln_kernel(
    const unsigned short* __restrict__ attn, const unsigned short* __restrict__ wt_out,
    const float* __restrict__ b_out, const float* __restrict__ src,
    const float* __restrict__ ln_g, const float* __restrict__ ln_b,
    unsigned short* __restrict__ src1, unsigned short* __restrict__ sn2, int M) {
  __shared__ unsigned short lds[4 * 4096];
  __shared__ float s_sum[64][4];
  __shared__ float s_sq[64][4];
  const int w = threadIdx.x >> 6, lane = threadIdx.x & 63;
  const int nwg = gridDim.x;    // 416
  const int bid = blockIdx.x;
  const int wgid = (bid & 7) * (nwg >> 3) + (bid >> 3);
  const int row0 = wgid * 64;
  const int col0 = w * 64;
  unsigned short* As = lds + w * 4096;
  unsigned short* Bs = As + 64 * 32;

  f32x4 acc[4][4] = {};
  const int frow = lane & 15;
  const int fke = ((lane >> 4) ^ ((frow >> 1) & 3)) * 8;

  stage64<256>(attn, wt_out, As, Bs, M, row0, col0, 0, lane);
  asm volatile("s_waitcnt vmcnt(0)" ::: "memory");
  #pragma unroll
  for (int k0 = 0; k0 < 256; k0 += 32) {
    short8 a[4], b[4];
    #pragma unroll
    for (int mi = 0; mi < 4; ++mi)
      a[mi] = *reinterpret_cast<const short8*>(&As[(mi * 16 + frow) * 32 + fke]);
    #pragma unroll
    for (int ni = 0; ni < 4; ++ni)
      b[ni] = *reinterpret_cast<const short8*>(&Bs[(ni * 16 + frow) * 32 + fke]);
    asm volatile("s_waitcnt lgkmcnt(0)" ::: "memory");
    __builtin_amdgcn_sched_barrier(0);
    if (k0 + 32 < 256)
      stage64<256>(attn, wt_out, As, Bs, M, row0, col0, k0 + 32, lane);
    #pragma unroll
    for (int mi = 0; mi < 4; ++mi)
      #pragma unroll
      for (int ni = 0; ni < 4; ++ni)
        acc[mi][ni] = __builtin_amdgcn_mfma_f32_16x16x32_bf16(b[ni], a[mi], acc[mi][ni], 0, 0, 0);
    if (k0 + 32 < 256)
      asm volatile("s_waitcnt vmcnt(0)" ::: "memory");
  }

  const int lr = lane & 15;
  const int cb = (lane >> 4) * 4;
  float lsum[4], lsq[4];
  #pragma unroll
  for (int mi = 0; mi < 4; ++mi) {
    const int grow = row0 + mi * 16 + lr;
    const bool ok = grow < M;
    float rs = 0.f, rq = 0.f;
    #pragma unroll
    for (int ni = 0; ni < 4; ++ni) {
      const int gcol = col0 + ni * 16 + cb;
      const float4 b4 = *reinterpret_cast<const float4*>(&b_out[gcol]);
      float4 r4 = make_float4(0.f, 0.f, 0.f, 0.f);
      if (ok) r4 = *reinterpret_cast<const float4*>(&src[(size_t)grow * 256 + gcol]);
      float v0 = acc[mi][ni][0] + b4.x + r4.x;
      float v1 = acc[mi][ni][1] + b4.y + r4.y;
      float v2 = acc[mi][ni][2] + b4.z + r4.z;
      float v3 = acc[mi][ni][3] + b4.w + r4.w;
      acc[mi][ni][0] = v0; acc[mi][ni][1] = v1;
      acc[mi][ni][2] = v2; acc[mi][ni][3] = v3;
      if (ok) {
        ushort4 o;
        o.x = f2bf(v0); o.y = f2bf(v1); o.z = f2bf(v2); o.w = f2bf(v3);
        *reinterpret_cast<ushort4*>(&src1[(size_t)grow * 256 + gcol]) = o;
      }
      rs += v0 + v1 + v2 + v3;
      rq += v0 * v0 + v1 * v1 + v2 * v2 + v3 * v3;
    }
    lsum[mi] = rs; lsq[mi] = rq;
  }
  #pragma unroll
  for (int mi = 0; mi < 4; ++mi) {
    lsum[mi] += __shfl_xor(lsum[mi], 16, 64);
    lsum[mi] += __shfl_xor(lsum[mi], 32, 64);
    lsq[mi]  += __shfl_xor(lsq[mi], 16, 64);
    lsq[mi]  += __shfl_xor(lsq[mi], 32, 64);
  }
  if (lane < 16) {
    #pragma unroll
    for (int mi = 0; mi < 4; ++mi) {
      s_sum[mi * 16 + lane][w] = lsum[mi];
      s_sq[mi * 16 + lane][w] = lsq[mi];
    }
  }
  __syncthreads();
  #pragma unroll
  for (int mi = 0; mi < 4; ++mi) {
    const int lrow = mi * 16 + lr;
    const int grow = row0 + lrow;
    if (grow >= M) continue;
    const float ssum = s_sum[lrow][0] + s_sum[lrow][1] + s_sum[lrow][2] + s_sum[lrow][3];
    const float ssq = s_sq[lrow][0] + s_sq[lrow][1] + s_sq[lrow][2] + s_sq[lrow][3];
    const float mean = ssum * (1.0f / 256.0f);
    const float var = ssq * (1.0f / 256.0f) - mean * mean;
    const float rinv = rsqrtf(var + 1e-5f);
    #pragma unroll
    for (int ni = 0; ni < 4; ++ni) {
      const int gcol = col0 + ni * 16 + cb;
      const float4 g4 = *reinterpret_cast<const float4*>(&ln_g[gcol]);
      const float4 bb = *reinterpret_cast<const float4*>(&ln_b[gcol]);
      ushort4 o;
      o.x = f2bf((acc[mi][ni][0] - mean) * rinv * g4.x + bb.x);
      o.y = f2bf((acc[mi][ni][1] - mean) * rinv * g4.y + bb.y);
      o.z = f2bf((acc[mi][ni][2] - mean) * rinv * g4.z + bb.z);
      o.w = f2bf((acc[mi][ni][3] - mean) * rinv * g4.w + bb.w);
      *reinterpret_cast<ushort4*>(&sn2[(size_t)grow * 256 + gcol]) = o;
    }
  }
}

// ---------------------------------------------------------------------------
// Fused softmax + deformable sampling — frozen R16/R19 config (unroll 8,
// float2 s_wi stride 66, 4 blocks/CU). 52.5us floor proven by two falsified
// alternatives (R17: +occupancy hurt; R21: +unroll hurt).
// ---------------------------------------------------------------------------
__global__ __launch_bounds__(256) void msda_kernel(
    const unsigned short* __restrict__ v, const unsigned short* __restrict__ offb,
    const unsigned short* __restrict__ awl, const float* __restrict__ ref,
    unsigned short* __restrict__ outb) {
  const int r0 = blockIdx.x * 8;
  const int tid = threadIdx.x;

  __shared__ float s_aw[8 * 128];
  __shared__ float s_ref[64];
  __shared__ float2 s_wi[64 * 66];   // group stride 66 (bank pad)

  if (tid < 64) {
    int rr = r0 + (tid >> 3); if (rr >= M_ROWS) rr = M_ROWS - 1;
    s_ref[tid] = ref[(size_t)rr * 8 + (tid & 7)];
  }

  {
    const int g = tid >> 2, j = tid & 3;
    const int tok = g >> 3, h = g & 7;
    int rr = r0 + tok; if (rr >= M_ROWS) rr = M_ROWS - 1;
    const uint2 u = *reinterpret_cast<const uint2*>(&awl[(size_t)rr * 128 + h * 16 + j * 4]);
    const float l0 = bf2f((unsigned short)(u.x & 0xffff));
    const float l1 = bf2f((unsigned short)(u.x >> 16));
    const float l2 = bf2f((unsigned short)(u.y & 0xffff));
    const float l3 = bf2f((unsigned short)(u.y >> 16));
    float mx = fmaxf(fmaxf(l0, l1), fmaxf(l2, l3));
    mx = fmaxf(mx, __shfl_xor(mx, 1, 64));
    mx = fmaxf(mx, __shfl_xor(mx, 2, 64));
    const float e0 = expf(l0 - mx), e1 = expf(l1 - mx);
    const float e2 = expf(l2 - mx), e3 = expf(l3 - mx);
    float ss = e0 + e1 + e2 + e3;
    ss += __shfl_xor(ss, 1, 64);
    ss += __shfl_xor(ss, 2, 64);
    const float inv = 1.0f / ss;
    float4 w4; w4.x = e0 * inv; w4.y = e1 * inv; w4.z = e2 * inv; w4.w = e3 * inv;
    *reinterpret_cast<float4*>(&s_aw[g * 16 + j * 4]) = w4;
  }
  __syncthreads();

  const int HH[4] = {100, 50, 25, 13};
  const int WW[4] = {100, 50, 25, 13};
  const int SS[4] = {0, 10000, 12500, 13125};

  {
    const int pi0 = tid * 4;
    const int tok = pi0 >> 7, h = (pi0 >> 4) & 7;
    const int g = pi0 >> 4;
    const int pt0 = pi0 & 15;
    const int l = pt0 >> 2;
    int rr = r0 + tok; if (rr >= M_ROWS) rr = M_ROWS - 1;
    const float Wl = (float)WW[l], Hl = (float)HH[l];
    const float rx = s_ref[tok * 8 + l * 2], ry = s_ref[tok * 8 + l * 2 + 1];
    const uint4 uoff = *reinterpret_cast<const uint4*>(&offb[(size_t)rr * 256 + h * 32 + pt0 * 2]);
    const float4 aw4 = *reinterpret_cast<const float4*>(&s_aw[g * 16 + pt0]);
    const unsigned int uo[4] = {uoff.x, uoff.y, uoff.z, uoff.w};
    const float awv[4] = {aw4.x, aw4.y, aw4.z, aw4.w};
    #pragma unroll
    for (int p = 0; p < 4; ++p) {
      const float ox = bf2f((unsigned short)(uo[p] & 0xffff));
      const float oy = bf2f((unsigned short)(uo[p] >> 16));
      const float x = rx * Wl + ox - 0.5f;
      const float y = ry * Hl + oy - 0.5f;
      const float x0f = floorf(x), y0f = floorf(y);
      const int x0 = (int)x0f, y0 = (int)y0f;
      const float wx1 = x - x0f, wy1 = y - y0f;
      const float wx0 = 1.f - wx1, wy0 = 1.f - wy1;
      const float aw = awv[p];
      #pragma unroll
      for (int c = 0; c < 4; ++c) {
        const int xx = x0 + (c & 1), yy = y0 + (c >> 1);
        const bool valid = (xx >= 0) & (xx < WW[l]) & (yy >= 0) & (yy < HH[l]);
        const int xc = min(max(xx, 0), WW[l] - 1);
        const int yc = min(max(yy, 0), HH[l] - 1);
        float wgt = aw * ((c & 1) ? wx1 : wx0) * ((c >> 1) ? wy1 : wy0);
        wgt = valid ? wgt : 0.f;
        const int idxb = (SS[l] + yc * WW[l] + xc) * 512;
        s_wi[g * 66 + (pt0 + p) * 4 + c] = make_float2(wgt, __int_as_float(idxb));
      }
    }
  }
  __syncthreads();

  const int tok = tid >> 5;
  const int h = (tid >> 2) & 7;
  const int d8 = tid & 3;
  const int r = r0 + tok;
  const int rc = (r < M_ROWS) ? r : M_ROWS - 1;
  const int b = rc / T_TOK;
  const char* vb = (const char*)(v + (size_t)b * T_TOK * 256 + h * 32 + d8 * 8);
  const int e0 = (tok * 8 + h) * 66;

  float a0 = 0.f, a1 = 0.f, a2 = 0.f, a3 = 0.f;
  float a4 = 0.f, a5 = 0.f, a6 = 0.f, a7 = 0.f;
  #pragma unroll 8
  for (int j = 0; j < 64; ++j) {
    const float2 wi = s_wi[e0 + j];
    const float wgt = wi.x;
    const int idxb = __float_as_int(wi.y);
    const uint4 u = *reinterpret_cast<const uint4*>(vb + idxb);
    a0 = fmaf(wgt, bf2f((unsigned short)(u.x & 0xffff)), a0);
    a1 = fmaf(wgt, bf2f((unsigned short)(u.x >> 16)), a1);
    a2 = fmaf(wgt, bf2f((unsigned short)(u.y & 0xffff)), a2);
    a3 = fmaf(wgt, bf2f((unsigned short)(u.y >> 16)), a3);
    a4 = fmaf(wgt, bf2f((unsigned short)(u.z & 0xffff)), a4);
    a5 = fmaf(wgt, bf2f((unsigned short)(u.z >> 16)), a5);
    a6 = fmaf(wgt, bf2f((unsigned short)(u.w & 0xffff)), a6);
    a7 = fmaf(wgt, bf2f((unsigned short)(u.w >> 16)), a7);
  }
  if (r < M_ROWS) {
    uint4 o;
    o.x = ((unsigned int)f2bf(a0)) | ((unsigned int)f2bf(a1) << 16);
    o.y = ((unsigned int)f2bf(a2)) | ((unsigned int)f2bf(a3) << 16);
    o.z = ((unsigned int)f2bf(a4)) | ((unsigned int)f2bf(a5) << 16);
    o.w = ((unsigned int)f2bf(a6)) | ((unsigned int)f2bf(a7) << 16);
    *reinterpret_cast<uint4*>(&outb[(size_t)r * 256 + h * 32 + d8 * 8]) = o;
  }
}

// ---------------------------------------------------------------------------
// Host launcher
// ---------------------------------------------------------------------------
extern "C" void kernel_launch(void* const* d_in, const int* in_sizes, int n_in,
                              void* d_out, int out_size, void* d_ws, size_t ws_size,
                              hipStream_t stream) {
  const float* src     = (const float*)d_in[0];
  const float* pos     = (const float*)d_in[1];
  const float* ref     = (const float*)d_in[2];
  const float* ln1_g   = (const float*)d_in[5];
  const float* ln1_b   = (const float*)d_in[6];
  const float* ln2_g   = (const float*)d_in[7];
  const float* ln2_b   = (const float*)d_in[8];
  const float* W_value = (const float*)d_in[9];
  const float* b_value = (const float*)d_in[10];
  const float* W_off   = (const float*)d_in[11];
  const float* b_off   = (const float*)d_in[12];
  const float* W_attn  = (const float*)d_in[13];
  const float* b_attn  = (const float*)d_in[14];
  const float* W_out   = (const float*)d_in[15];
  const float* b_out   = (const float*)d_in[16];
  const float* W_ffn1  = (const float*)d_in[17];
  const float* b_ffn1  = (const float*)d_in[18];
  const float* W_ffn2  = (const float*)d_in[19];
  const float* b_ffn2  = (const float*)d_in[20];
  float* out = (float*)d_out;

  const int M = M_ROWS;
  const size_t n256 = (size_t)M * 256;

  // workspace layout
  unsigned short* src_n_bf = (unsigned short*)d_ws;
  unsigned short* q_bf     = src_n_bf + n256;
  unsigned short* v_bf     = q_bf + n256;
  unsigned short* attn_bf  = v_bf + n256;
  unsigned short* sn2_bf   = attn_bf + n256;
  unsigned short* hid_bf   = sn2_bf + n256;                  // M*1024
  unsigned short* offb     = hid_bf + (size_t)M * 1024;      // M*256 bf16
  unsigned short* awbuf    = offb + n256;                    // M*128 bf16
  unsigned short* src1_bf  = awbuf + (size_t)M * 128;        // M*256 bf16
  unsigned short* wt_val     = src1_bf + n256;
  unsigned short* wt_offattn = wt_val + 256 * 256;            // [384,256]
  unsigned short* wt_out     = wt_offattn + 384 * 256;
  unsigned short* wt_ffn1    = wt_out + 256 * 256;
  unsigned short* wt_ffn2    = wt_ffn1 + 1024 * 256;

  // 0+1. weight transposes + LN1 fused
  prep_kernel<<<736 + (M + 3) / 4, 256, 0, stream>>>(
      W_value, W_off, W_attn, W_out, W_ffn1, W_ffn2,
      wt_val, wt_offattn, wt_offattn + 256 * 256, wt_out, wt_ffn1, wt_ffn2,
      src, pos, ln1_g, ln1_b, src_n_bf, q_bf);

  // 2. value proj + off/attn proj: 4160 one-wave blocks (BK=64)
  wproj64_fused<<<4160, 64, 0, stream>>>(
      src_n_bf, q_bf, wt_val, wt_offattn, b_value, b_off, b_attn,
      v_bf, offb, awbuf, M);

  // 3. softmax + sampling (8 tokens/block)
  msda_kernel<<<(M + 7) / 8, 256, 0, stream>>>(v_bf, offb, awbuf, ref, attn_bf);

  // 4. out-proj + residual + LN2 fused -> src1 (bf16) + sn2 (bf16)
  outln_kernel<<<416, 256, 0, stream>>>(attn_bf, wt_out, b_out, src,
                                        ln2_g, ln2_b, src1_bf, sn2_bf, M);

  // 5. FFN (BK=64 one-wave blocks; ffn2 residual = bf16 src1, EPI 4)
  wgemm64_k<1, true, 256 ><<<6656, 64, 0, stream>>>(sn2_bf, wt_ffn1, b_ffn1, nullptr,
                                                    hid_bf, M, 1024);
  wgemm64_k<4, false, 1024><<<1664, 64, 0, stream>>>(hid_bf, wt_ffn2, b_ffn2,
                                                     (const float*)src1_bf,
                                                     out, M, 256);
}